// Round 14
// baseline (180.178 us; speedup 1.0000x reference)
//
#include <hip/hip_runtime.h>
#include <cstdint>

// CapsuleLayer dynamic routing: B=256, R=1152, C=10, O=16, I=8, 3 iters.
// fp32 in, fp32 out. Block = (c, 2 batches), 512 threads, 2 blocks/CU.
// Round-14 = round-13 with the DPP ctrl as a template arg (must be an
// immediate). Theory unchanged: rounds 10-12 flat at ~100us despite +TLP
// => throughput-saturated TA + LDS pipes, not latency:
//  - Phase 1: lanes = 2r x 32q, W loads fully contiguous (16 line-req/KB
//    instead of 64/KB); half-dots combined via DPP quad_perm (VALU).
//  - u stored r-major 32 B/row, 16B-chunk XOR swizzle by (r>>2)&1:
//    phase-2 reads are 2x ds_read_b128/row, conflict-free.
//  - Reductions on VALU via DPP row_shr (sum at row-lane 15), not
//    ds_swizzle butterflies (was ~400 DS ops/thread).
// b_ij never stored: with b0=0, logit_k = u . (v0 + ... + v_{k-1}).
#define BB 256
#define RR 1152
#define CC 10
#define OO 16
#define II 8
#define NT 512
#define GG 2
#define NWAVE (NT / 64)
#define UHALF (RR * 16)        // halfwords per batch u-region (36,864 B)

__device__ __forceinline__ uint32_t f2bf(float f) {
    union { float f; uint32_t i; } v; v.f = f;
    return (v.i + 0x7fffu + ((v.i >> 16) & 1u)) >> 16;   // RNE
}
__device__ __forceinline__ void unpack2(uint32_t pk, float& lo, float& hi) {
    union { uint32_t i; float f; } a, b;
    a.i = pk << 16; b.i = pk & 0xffff0000u;
    lo = a.f; hi = b.f;
}
// v += dpp(v); CTRL immediate via template; bound_ctrl=true -> OOB reads 0
template <int CTRL>
__device__ __forceinline__ float dpp_add(float v) {
    return v + __int_as_float(__builtin_amdgcn_update_dpp(
        0, __float_as_int(v), CTRL, 0xf, 0xf, true));
}
// 16-lane row sum; result lands in row-local lane 15 (row_shr shifts up)
__device__ __forceinline__ float row16_sum(float v) {
    v = dpp_add<0x111>(v);   // row_shr:1
    v = dpp_add<0x112>(v);   // row_shr:2
    v = dpp_add<0x114>(v);   // row_shr:4
    v = dpp_add<0x118>(v);   // row_shr:8
    return v;
}

__global__ __launch_bounds__(NT)
__attribute__((amdgpu_waves_per_eu(2, 4)))
void k_caps(const float* __restrict__ x, const float* __restrict__ W,
            float* __restrict__ out) {
    extern __shared__ uint16_t uh[];        // [GG][RR][16] bf16, chunk-swizzled
    __shared__ float part[GG][32][17];
    __shared__ float wsum[GG][OO];

    const int t = threadIdx.x;
    const int c  = blockIdx.x / (BB / GG);  // c-major: 128 blocks share W-slice
    const int b0 = (blockIdx.x % (BB / GG)) * GG;
    const int wv = t >> 6, l = t & 63;

    // ---- Phase 1: u = W.x for both batches -> LDS; fused pass-0 sums ----
    const int rs = l >> 5;                  // r_sub 0..1
    const int q  = l & 31;                  // 16B chunk of the 512B c-slice
    const int o1 = q >> 1, h1 = q & 1;      // o, input-half
    float s0a = 0.f, s0b = 0.f;

#pragma unroll 2
    for (int i = 0; i < RR / (NWAVE * 2); ++i) {          // 72 iterations
        const int r = (i * NWAVE + wv) * 2 + rs;
        // W[r,c, o1, 4*h1 ..]: lane q at base + 16B*q -> 1KB contiguous/wave
        const float* wp = W + ((size_t)r * CC + c) * (OO * II) + q * 4;
        float4 wf = *reinterpret_cast<const float4*>(wp);
        const float* xp = x + ((size_t)b0 * RR + r) * II + h1 * 4;
        float4 xa = *reinterpret_cast<const float4*>(xp);
        float4 xb = *reinterpret_cast<const float4*>(xp + (size_t)RR * II);
        float ua = 0.f, ub = 0.f;
        ua = fmaf(wf.x, xa.x, ua); ua = fmaf(wf.y, xa.y, ua);
        ua = fmaf(wf.z, xa.z, ua); ua = fmaf(wf.w, xa.w, ua);
        ub = fmaf(wf.x, xb.x, ub); ub = fmaf(wf.y, xb.y, ub);
        ub = fmaf(wf.z, xb.z, ub); ub = fmaf(wf.w, xb.w, ub);
        // combine the two input-halves within the quad (q ^ 1): VALU DPP
        ua = dpp_add<0xB1>(ua);             // quad_perm [1,0,3,2]
        ub = dpp_add<0xB1>(ub);
        s0a += ua; s0b += ub;
        if ((l & 1) == 0) {                 // h==0 lane holds u[g][r][o1]
            const int hsw = (o1 >> 3) ^ ((r >> 2) & 1);   // 16B-chunk swizzle
            const int widx = r * 16 + hsw * 8 + (o1 & 7);
            uh[widx] = (uint16_t)f2bf(ua);
            uh[UHALF + widx] = (uint16_t)f2bf(ub);
        }
    }
    // pass-0 partials: sum over r_sub groups (lanes ^32); h-duplicates ok
    s0a += __shfl_xor(s0a, 32);
    s0b += __shfl_xor(s0b, 32);
    if (l < 32 && (l & 1) == 0) {
        part[0][wv][o1] = s0a;
        part[1][wv][o1] = s0b;
    }
    __syncthreads();
    if (t < GG * OO) {                      // g = t>>4, o = t&15
        const int g = t >> 4, o = t & 15;
        float s = 0.f;
#pragma unroll
        for (int w = 0; w < NWAVE; ++w) s += part[g][w][o];
        s *= (1.0f / RR);                   // softmax(0) = 1/R
        float ss = s * s;                   // squash over 16-lane o-group
        ss += __shfl_xor(ss, 1); ss += __shfl_xor(ss, 2);
        ss += __shfl_xor(ss, 4); ss += __shfl_xor(ss, 8);
        wsum[g][o] = s * (ss / ((1.0f + ss) * sqrtf(ss + 1e-7f)));  // v0
    }
    __syncthreads();

    // ---- Phase 2: passes 1 and 2; u rows via ds_read_b128 ----
    for (int pass = 1; pass < 3; ++pass) {
#pragma unroll
        for (int g = 0; g < GG; ++g) {
            const uint16_t* ug = uh + g * UHALF;
            float wreg[OO];
#pragma unroll
            for (int k = 0; k < OO; ++k) wreg[k] = wsum[g][k];  // broadcast
            float num[OO];
#pragma unroll
            for (int k = 0; k < OO; ++k) num[k] = 0.f;
            float den = 0.f;

#pragma unroll
            for (int kk = 0; kk < 3; ++kk) {
                const int r = t + 512 * kk;
                if (kk < 2 || t < RR - 1024) {              // wave-uniform
                    const int bit = (r >> 2) & 1;
                    const uint32_t* rowp =
                        reinterpret_cast<const uint32_t*>(ug + (size_t)r * 16);
                    uint4 qlo = *reinterpret_cast<const uint4*>(rowp + 4 * bit);
                    uint4 qhi = *reinterpret_cast<const uint4*>(rowp + 4 * (bit ^ 1));
                    float ur[OO];
                    unpack2(qlo.x, ur[0], ur[1]);   unpack2(qlo.y, ur[2], ur[3]);
                    unpack2(qlo.z, ur[4], ur[5]);   unpack2(qlo.w, ur[6], ur[7]);
                    unpack2(qhi.x, ur[8], ur[9]);   unpack2(qhi.y, ur[10], ur[11]);
                    unpack2(qhi.z, ur[12], ur[13]); unpack2(qhi.w, ur[14], ur[15]);
                    float lg = 0.f;
#pragma unroll
                    for (int k = 0; k < OO; ++k) lg = fmaf(ur[k], wreg[k], lg);
                    float e = __expf(lg);   // |logit| <~ 40: fp32-safe
                    den += e;
#pragma unroll
                    for (int k = 0; k < OO; ++k) num[k] = fmaf(e, ur[k], num[k]);
                }
            }
            // 16-lane reduction on the VALU (DPP); sum at row-lane 15
#pragma unroll
            for (int k = 0; k < OO; ++k) num[k] = row16_sum(num[k]);
            den = row16_sum(den);
            if ((l & 15) == 15) {
                const int row = (wv << 2) + (l >> 4);
#pragma unroll
                for (int k = 0; k < OO; ++k) part[g][row][k] = num[k];
                part[g][row][16] = den;
            }
        }
        __syncthreads();

        if (t < GG * OO) {
            const int g = t >> 4, o = t & 15;
            float nf = 0.f, df = 0.f;
#pragma unroll
            for (int j = 0; j < 32; ++j) {
                nf += part[g][j][o];
                df += part[g][j][16];
            }
            float s = nf / df;
            float ss = s * s;
            ss += __shfl_xor(ss, 1); ss += __shfl_xor(ss, 2);
            ss += __shfl_xor(ss, 4); ss += __shfl_xor(ss, 8);
            float v = s * (ss / ((1.0f + ss) * sqrtf(ss + 1e-7f)));
            if (pass == 2)
                out[((size_t)(b0 + g) * CC + c) * OO + o] = v;
            else
                wsum[g][o] += v;
        }
        __syncthreads();
    }
}

extern "C" void kernel_launch(void* const* d_in, const int* in_sizes, int n_in,
                              void* d_out, int out_size, void* d_ws, size_t ws_size,
                              hipStream_t stream) {
    const float* x = (const float*)d_in[0];  // (B,R,I) fp32
    const float* W = (const float*)d_in[1];  // (R,C,O,I) fp32
    if (n_in >= 2 && in_sizes[0] == RR * CC * OO * II &&
        in_sizes[1] == BB * RR * II) {
        const float* tmp = x; x = W; W = tmp;
    }
    float* out = (float*)d_out;              // (B,1,C,O,1) fp32

    const size_t dyn_lds = (size_t)GG * RR * 16 * 2;   // 73,728 B
    k_caps<<<CC * (BB / GG), NT, dyn_lds, stream>>>(x, W, out);
}

// Round 15
// 152.917 us; speedup vs baseline: 1.1783x; 1.1783x over previous
//
#include <hip/hip_runtime.h>
#include <cstdint>

// CapsuleLayer dynamic routing: B=256, R=1152, C=10, O=16, I=8, 3 iters.
// fp32 in, fp32 out. Round-15: block = (c, 4 batches), 1024 threads,
// 1 block/CU (148 KB dynamic LDS), 4 waves/SIMD. Halves the dominant
// TA-line-request term vs GG=2 (W-slice read once per block, reused 4x).
// u kept in LDS as packed bf16 pairs, p-stride PSTR (%32==5): consecutive
// lanes hit consecutive banks -> conflict-free (round 12 verified; round
// 14's 32B-row layout was 16-way conflicted -> regression). Reductions on
// the VALU via DPP (row_shr 1/2/4/8 + row_bcast 15/31, sum lands in lane
// 63) -- removes ~400 ds_bpermute ops/thread from the DS pipe; row_shr
// part numerically verified in round 14. b_ij never stored: with b0=0,
// logit_k = u . (v0 + ... + v_{k-1}).
#define BB 256
#define RR 1152
#define CC 10
#define OO 16
#define II 8
#define NT 1024
#define GG 4
#define NWAVE (NT / 64)        // 16
#define NIT (RR / (NT / 8))    // 9 phase-1 iterations (128 r-rows each)
#define PSTR 1157              // p-row stride in words; 1157 % 32 == 5

__device__ __forceinline__ uint32_t f2bf(float f) {
    union { float f; uint32_t i; } v; v.f = f;
    return (v.i + 0x7fffu + ((v.i >> 16) & 1u)) >> 16;   // RNE
}
__device__ __forceinline__ void unpack2(uint32_t pk, float& lo, float& hi) {
    union { uint32_t i; float f; } a, b;
    a.i = pk << 16; b.i = pk & 0xffff0000u;
    lo = a.f; hi = b.f;
}
template <int CTRL>
__device__ __forceinline__ float dpp_add(float v) {
    return v + __int_as_float(__builtin_amdgcn_update_dpp(
        0, __float_as_int(v), CTRL, 0xf, 0xf, true));
}
// canonical 64-lane sum on the VALU; total lands in lane 63
__device__ __forceinline__ float wave64_sum(float v) {
    v = dpp_add<0x111>(v);   // row_shr:1
    v = dpp_add<0x112>(v);   // row_shr:2
    v = dpp_add<0x114>(v);   // row_shr:4
    v = dpp_add<0x118>(v);   // row_shr:8  -> row sums in lanes 15/31/47/63
    v = dpp_add<0x142>(v);   // row_bcast:15 -> lane31 = r0+r1, lane63 = r2+r3
    v = dpp_add<0x143>(v);   // row_bcast:31 -> lane63 = all four rows
    return v;
}

__global__ __launch_bounds__(NT)
void k_caps(const float* __restrict__ x, const float* __restrict__ W,
            float* __restrict__ out) {
    extern __shared__ uint32_t u2[];          // [GG][8][PSTR] packed bf16 pairs
    __shared__ float part[GG][NWAVE][17];
    __shared__ float p0s[NWAVE][8][GG][2];    // [wv][p][g][half]
    __shared__ float wsum[GG][OO];

    const int t = threadIdx.x;
    const int c  = blockIdx.x / (BB / GG);    // c-major: 64 blocks share W-slice
    const int b0 = (blockIdx.x % (BB / GG)) * GG;
    const int wv = t >> 6, l = t & 63;
    const int rg = t >> 3, p = t & 7;         // phase 1: 128 r-rows x 8 o-pairs

    // ---- Phase 1: u[r,2p:2p+2] for 4 batches -> LDS; fused pass-0 sums ----
    float s0[GG][2];
#pragma unroll
    for (int g = 0; g < GG; ++g) { s0[g][0] = 0.f; s0[g][1] = 0.f; }

    for (int it = 0; it < NIT; ++it) {
        const int r = it * (NT / 8) + rg;
        const float* wp = W + (((size_t)r * CC + c) * OO + 2 * p) * II;
        float4 a0 = *reinterpret_cast<const float4*>(wp);
        float4 a1 = *reinterpret_cast<const float4*>(wp + 4);
        float4 c0 = *reinterpret_cast<const float4*>(wp + 8);
        float4 c1 = *reinterpret_cast<const float4*>(wp + 12);
#pragma unroll
        for (int g = 0; g < GG; ++g) {
            const float* xp = x + ((size_t)(b0 + g) * RR + r) * II;
            float4 x0 = *reinterpret_cast<const float4*>(xp);
            float4 x1 = *reinterpret_cast<const float4*>(xp + 4);
            float lo = 0.f, hi = 0.f;
            lo = fmaf(a0.x, x0.x, lo); lo = fmaf(a0.y, x0.y, lo);
            lo = fmaf(a0.z, x0.z, lo); lo = fmaf(a0.w, x0.w, lo);
            lo = fmaf(a1.x, x1.x, lo); lo = fmaf(a1.y, x1.y, lo);
            lo = fmaf(a1.z, x1.z, lo); lo = fmaf(a1.w, x1.w, lo);
            hi = fmaf(c0.x, x0.x, hi); hi = fmaf(c0.y, x0.y, hi);
            hi = fmaf(c0.z, x0.z, hi); hi = fmaf(c0.w, x0.w, hi);
            hi = fmaf(c1.x, x1.x, hi); hi = fmaf(c1.y, x1.y, hi);
            hi = fmaf(c1.z, x1.z, hi); hi = fmaf(c1.w, x1.w, hi);
            s0[g][0] += lo; s0[g][1] += hi;
            u2[g * 8 * PSTR + p * PSTR + r] = f2bf(lo) | (f2bf(hi) << 16);
        }
    }
    // reduce pass-0 partials over the 8 r-lanes sharing p (masks 8,16,32)
#pragma unroll
    for (int m = 8; m < 64; m <<= 1) {
#pragma unroll
        for (int g = 0; g < GG; ++g) {
            s0[g][0] += __shfl_xor(s0[g][0], m);
            s0[g][1] += __shfl_xor(s0[g][1], m);
        }
    }
    if (l < 8) {
#pragma unroll
        for (int g = 0; g < GG; ++g) {
            p0s[wv][l][g][0] = s0[g][0];
            p0s[wv][l][g][1] = s0[g][1];
        }
    }
    __syncthreads();

    if (t < GG * OO) {                        // g = t>>4, o = t&15 (wave 0)
        const int g = t >> 4, o = t & 15;
        float s = 0.f;
#pragma unroll
        for (int w = 0; w < NWAVE; ++w) s += p0s[w][o >> 1][g][o & 1];
        s *= (1.0f / RR);                     // softmax(0) = 1/R
        float ss = s * s;                     // squash over 16-lane o-group
        ss += __shfl_xor(ss, 1); ss += __shfl_xor(ss, 2);
        ss += __shfl_xor(ss, 4); ss += __shfl_xor(ss, 8);
        wsum[g][o] = s * (ss / ((1.0f + ss) * sqrtf(ss + 1e-7f)));  // v0
    }
    __syncthreads();

    // ---- Phase 2: passes 1 and 2 from LDS (conflict-free b32 reads) ----
    for (int pass = 1; pass < 3; ++pass) {
#pragma unroll
        for (int g = 0; g < GG; ++g) {
            const uint32_t* ug = u2 + g * 8 * PSTR;
            float wreg[OO];
#pragma unroll
            for (int k = 0; k < OO; ++k) wreg[k] = wsum[g][k];  // broadcast
            float num[OO];
#pragma unroll
            for (int k = 0; k < OO; ++k) num[k] = 0.f;
            float den = 0.f;

#pragma unroll
            for (int kk = 0; kk < 2; ++kk) {
                const int r = t + NT * kk;
                if (kk == 0 || t < RR - NT) {             // wave-uniform guard
                    float ur[OO];
#pragma unroll
                    for (int pp = 0; pp < 8; ++pp)        // bank=(5pp+r)%32: free
                        unpack2(ug[pp * PSTR + r], ur[2 * pp], ur[2 * pp + 1]);
                    float lg = 0.f;
#pragma unroll
                    for (int k = 0; k < OO; ++k) lg = fmaf(ur[k], wreg[k], lg);
                    float e = __expf(lg);                 // |logit| <~ 40: safe
                    den += e;
#pragma unroll
                    for (int k = 0; k < OO; ++k) num[k] = fmaf(e, ur[k], num[k]);
                }
            }
            // 64-lane reduction on the VALU (DPP); totals in lane 63
#pragma unroll
            for (int k = 0; k < OO; ++k) num[k] = wave64_sum(num[k]);
            den = wave64_sum(den);
            if (l == 63) {
#pragma unroll
                for (int k = 0; k < OO; ++k) part[g][wv][k] = num[k];
                part[g][wv][16] = den;
            }
        }
        __syncthreads();

        if (t < GG * OO) {
            const int g = t >> 4, o = t & 15;
            float nf = 0.f, df = 0.f;
#pragma unroll
            for (int w = 0; w < NWAVE; ++w) {
                nf += part[g][w][o];
                df += part[g][w][16];
            }
            float s = nf / df;
            float ss = s * s;
            ss += __shfl_xor(ss, 1); ss += __shfl_xor(ss, 2);
            ss += __shfl_xor(ss, 4); ss += __shfl_xor(ss, 8);
            float v = s * (ss / ((1.0f + ss) * sqrtf(ss + 1e-7f)));
            if (pass == 2)
                out[((size_t)(b0 + g) * CC + c) * OO + o] = v;
            else
                wsum[g][o] += v;
        }
        __syncthreads();
    }
}

extern "C" void kernel_launch(void* const* d_in, const int* in_sizes, int n_in,
                              void* d_out, int out_size, void* d_ws, size_t ws_size,
                              hipStream_t stream) {
    const float* x = (const float*)d_in[0];  // (B,R,I) fp32
    const float* W = (const float*)d_in[1];  // (R,C,O,I) fp32
    if (n_in >= 2 && in_sizes[0] == RR * CC * OO * II &&
        in_sizes[1] == BB * RR * II) {
        const float* tmp = x; x = W; W = tmp;
    }
    float* out = (float*)d_out;              // (B,1,C,O,1) fp32

    const size_t dyn_lds = (size_t)GG * 8 * PSTR * 4;   // 148,096 B
    k_caps<<<CC * (BB / GG), NT, dyn_lds, stream>>>(x, W, out);
}